// Round 7
// baseline (561.548 us; speedup 1.0000x reference)
//
#include <hip/hip_runtime.h>

#define M_ROWS 200000
#define NROWS  64            // rows per block
#define NBLK   3125          // 200000 / 64, exact
#define DIM1   320
#define OUTD   416
#define FSTR   196           // feat row stride (floats): 16B-aligned; quad-stride -> 2-way max

#define SCAL_STR 9
#define SCAL_OFF (NROWS * FSTR)
#define LDS_FLOATS (SCAL_OFF + NROWS * SCAL_STR)

typedef __attribute__((ext_vector_type(4))) float f32x4;

static __device__ __forceinline__ float4 ld4(const float* p) {
    return *reinterpret_cast<const float4*>(p);
}

__global__ __launch_bounds__(256, 2)
void tp_valu_v7(const float* __restrict__ x1,
                const float* __restrict__ x2,
                const float* __restrict__ w000,
                const float* __restrict__ w011,
                const float* __restrict__ w101,
                const float* __restrict__ w110,
                const float* __restrict__ w112,
                float* __restrict__ out) {
    __shared__ float lds[LDS_FLOATS];
    float* feat = lds;
    float* scal = lds + SCAL_OFF;

    constexpr float INV3 = 0.57735026918962576f;   // 1/sqrt(3)
    constexpr float INV6 = 0.40824829046386302f;   // 1/sqrt(6)

    const int t   = threadIdx.x;
    const int row = t & 63;                        // staging row
    const int q   = t >> 6;                        // staging quarter / wave id
    const int wvu = __builtin_amdgcn_readfirstlane(q);
    const long rbase = (long)blockIdx.x * NROWS;

    const float* x1r = x1 + (rbase + row) * DIM1;
    float* frS = feat + row * FSTR;

    const float4 xr2 = ld4(x2 + (rbase + row) * 4);
    const float s2 = xr2.x, vx = xr2.y, vy = xr2.z, vz = xr2.w;
    if (q == 0) {
        scal[row*SCAL_STR+0] = s2;
        scal[row*SCAL_STR+1] = s2 * INV3;
        scal[row*SCAL_STR+2] = vx * INV3;
        scal[row*SCAL_STR+3] = vy * INV3;
        scal[row*SCAL_STR+4] = vz * INV3;
    }

    // ---------------- stage S: featA = [x1s raw (0..127) | d*INV3 (128..191)] ----------------
    {
        #pragma unroll
        for (int i = 0; i < 8; ++i) {
            float4 v = ld4(x1r + q*32 + 4*i);
            *reinterpret_cast<float4*>(frS + q*32 + 4*i) = v;
        }
        float qf[48];
        #pragma unroll
        for (int c = 0; c < 12; ++c) {
            float4 v = ld4(x1r + 128 + 48*q + 4*c);
            qf[4*c+0]=v.x; qf[4*c+1]=v.y; qf[4*c+2]=v.z; qf[4*c+3]=v.w;
        }
        #pragma unroll
        for (int i = 0; i < 16; ++i) {
            const int u = 16*q + i;
            frS[128 + u] = (qf[3*i]*vx + qf[3*i+1]*vy + qf[3*i+2]*vz) * INV3;
        }
    }
    __syncthreads();

    // compute-phase thread map: 4 rows per thread (quad), col chunk cc
    const int quad = t >> 4;                       // 0..15 -> rows 4*quad..4*quad+3
    const int cc   = t & 15;                       // col chunk
    const int r0   = 4 * quad;
    const float* f0 = feat + (r0 + 0) * FSTR;
    const float* f1 = feat + (r0 + 1) * FSTR;
    const float* f2 = feat + (r0 + 2) * FSTR;
    const float* f3 = feat + (r0 + 3) * FSTR;

    // 8-col FMA step: qq[r][0..3] features at FOFF, W float4[8] = 4 k-rows x 8 cols
    #define FMAS8(ACC, W, FOFF)                                              \
      do {                                                                   \
        f32x4 qq[4];                                                         \
        qq[0] = *reinterpret_cast<const f32x4*>(f0 + (FOFF));                \
        qq[1] = *reinterpret_cast<const f32x4*>(f1 + (FOFF));                \
        qq[2] = *reinterpret_cast<const f32x4*>(f2 + (FOFF));                \
        qq[3] = *reinterpret_cast<const f32x4*>(f3 + (FOFF));                \
        _Pragma("unroll")                                                    \
        for (int r_ = 0; r_ < 4; ++r_) {                                     \
          _Pragma("unroll")                                                  \
          for (int dk_ = 0; dk_ < 4; ++dk_) {                                \
            const float fv_ = qq[r_][dk_];                                   \
            const float4 wlo_ = W[2*dk_], whi_ = W[2*dk_+1];                 \
            ACC[r_*8+0] += fv_*wlo_.x;  ACC[r_*8+1] += fv_*wlo_.y;           \
            ACC[r_*8+2] += fv_*wlo_.z;  ACC[r_*8+3] += fv_*wlo_.w;           \
            ACC[r_*8+4] += fv_*whi_.x;  ACC[r_*8+5] += fv_*whi_.y;           \
            ACC[r_*8+6] += fv_*whi_.z;  ACC[r_*8+7] += fv_*whi_.w;           \
          }                                                                  \
        }                                                                    \
      } while (0)

    #define LOADW8(W, BASE, KT)                                              \
      do {                                                                   \
        const float* wp_ = (BASE) + (size_t)(4*(KT))*128;                    \
        _Pragma("unroll")                                                    \
        for (int dk_ = 0; dk_ < 4; ++dk_) {                                  \
          W[2*dk_]   = ld4(wp_ + dk_*128);                                   \
          W[2*dk_+1] = ld4(wp_ + dk_*128 + 4);                               \
        }                                                                    \
      } while (0)

    // 4-col FMA step (ldn=64): W float4[4] = 4 k-rows x 4 cols
    #define FMAS4(ACC, W, FOFF)                                              \
      do {                                                                   \
        f32x4 qq[4];                                                         \
        qq[0] = *reinterpret_cast<const f32x4*>(f0 + (FOFF));                \
        qq[1] = *reinterpret_cast<const f32x4*>(f1 + (FOFF));                \
        qq[2] = *reinterpret_cast<const f32x4*>(f2 + (FOFF));                \
        qq[3] = *reinterpret_cast<const f32x4*>(f3 + (FOFF));                \
        _Pragma("unroll")                                                    \
        for (int r_ = 0; r_ < 4; ++r_) {                                     \
          _Pragma("unroll")                                                  \
          for (int dk_ = 0; dk_ < 4; ++dk_) {                                \
            const float fv_ = qq[r_][dk_];                                   \
            const float4 w_ = W[dk_];                                        \
            ACC[r_*4+0] += fv_*w_.x;  ACC[r_*4+1] += fv_*w_.y;               \
            ACC[r_*4+2] += fv_*w_.z;  ACC[r_*4+3] += fv_*w_.w;               \
          }                                                                  \
        }                                                                    \
      } while (0)

    #define LOADW4(W, BASE, KT)                                              \
      do {                                                                   \
        const float* wp_ = (BASE) + (size_t)(4*(KT))*64;                     \
        _Pragma("unroll")                                                    \
        for (int dk_ = 0; dk_ < 4; ++dk_) W[dk_] = ld4(wp_ + dk_*64);        \
      } while (0)

    // ---------------- P1: out0 (A: K=128 w000, D: K=64 w110), cols 8*cc ----------------
    {
        const int c8 = cc * 8;
        float accA[32], accD[32];
        #pragma unroll
        for (int i = 0; i < 32; ++i) { accA[i] = 0.f; accD[i] = 0.f; }

        {   // A-part: kt 0..31
            const float* wb = w000 + c8;
            float4 wA[8], wB[8];
            LOADW8(wA, wb, 0);
            for (int kp = 0; kp < 16; ++kp) {
                const int ktA = 2*kp;
                LOADW8(wB, wb, ktA+1);
                FMAS8(accA, wA, 4*ktA);
                LOADW8(wA, wb, (kp < 15) ? ktA+2 : 30);
                FMAS8(accA, wB, 4*(ktA+1));
            }
        }
        {   // D-part: kt 0..15, features at 128+
            const float* wb = w110 + c8;
            float4 wA[8], wB[8];
            LOADW8(wA, wb, 0);
            for (int kp = 0; kp < 8; ++kp) {
                const int ktA = 2*kp;
                LOADW8(wB, wb, ktA+1);
                FMAS8(accD, wA, 128 + 4*ktA);
                LOADW8(wA, wb, (kp < 7) ? ktA+2 : 14);
                FMAS8(accD, wB, 128 + 4*(ktA+1));
            }
        }

        #pragma unroll
        for (int r = 0; r < 4; ++r) {
            const float s2r = scal[(r0 + r)*SCAL_STR + 0];
            float* orow = out + (rbase + r0 + r)*OUTD + c8;
            float4 o0, o1;
            o0.x = s2r*accA[r*8+0] + accD[r*8+0];
            o0.y = s2r*accA[r*8+1] + accD[r*8+1];
            o0.z = s2r*accA[r*8+2] + accD[r*8+2];
            o0.w = s2r*accA[r*8+3] + accD[r*8+3];
            o1.x = s2r*accA[r*8+4] + accD[r*8+4];
            o1.y = s2r*accA[r*8+5] + accD[r*8+5];
            o1.z = s2r*accA[r*8+6] + accD[r*8+6];
            o1.w = s2r*accA[r*8+7] + accD[r*8+7];
            *reinterpret_cast<float4*>(orow)     = o0;
            *reinterpret_cast<float4*>(orow + 4) = o1;
        }
    }

    // ---------------- P2: out1 b-part (K=128 w011), cols 4*cc; acc held across barriers ----------------
    const int c4 = cc * 4;
    float accB[16];
    #pragma unroll
    for (int i = 0; i < 16; ++i) accB[i] = 0.f;
    {
        const float* wb = w011 + c4;
        float4 wA[4], wB[4];
        LOADW4(wA, wb, 0);
        for (int kp = 0; kp < 16; ++kp) {
            const int ktA = 2*kp;
            LOADW4(wB, wb, ktA+1);
            FMAS4(accB, wA, 4*ktA);
            LOADW4(wA, wb, (kp < 15) ? ktA+2 : 30);
            FMAS4(accB, wB, 4*(ktA+1));
        }
    }
    __syncthreads();

    // ---------------- stage T: featT = [v0 | v1 | v2] ----------------
    {
        float qf[48];
        #pragma unroll
        for (int c = 0; c < 12; ++c) {
            float4 v = ld4(x1r + 128 + 48*q + 4*c);
            qf[4*c+0]=v.x; qf[4*c+1]=v.y; qf[4*c+2]=v.z; qf[4*c+3]=v.w;
        }
        #pragma unroll
        for (int i = 0; i < 16; ++i) {
            const int u = 16*q + i;
            frS[u]       = qf[3*i+0];
            frS[64 + u]  = qf[3*i+1];
            frS[128 + u] = qf[3*i+2];
        }
    }
    __syncthreads();

    // ---------------- P3: out1 e-part (K=64 w101, 3 comps) + epilogue ----------------
    {
        float accE0[16], accE1[16], accE2[16];
        #pragma unroll
        for (int i = 0; i < 16; ++i) { accE0[i]=0.f; accE1[i]=0.f; accE2[i]=0.f; }

        const float* wb = w101 + c4;
        float4 wA[4], wB[4];
        LOADW4(wA, wb, 0);
        for (int up = 0; up < 8; ++up) {
            const int utA = 2*up;
            LOADW4(wB, wb, utA+1);
            FMAS4(accE0, wA, 4*utA);
            FMAS4(accE1, wA, 64 + 4*utA);
            FMAS4(accE2, wA, 128 + 4*utA);
            LOADW4(wA, wb, (up < 7) ? utA+2 : 14);
            FMAS4(accE0, wB, 4*(utA+1));
            FMAS4(accE1, wB, 64 + 4*(utA+1));
            FMAS4(accE2, wB, 128 + 4*(utA+1));
        }

        #pragma unroll
        for (int r = 0; r < 4; ++r) {
            const int rw = r0 + r;
            const float s2I = scal[rw*SCAL_STR+1];
            const float vxI = scal[rw*SCAL_STR+2];
            const float vyI = scal[rw*SCAL_STR+3];
            const float vzI = scal[rw*SCAL_STR+4];
            float vals[12];
            #pragma unroll
            for (int cj = 0; cj < 4; ++cj) {
                const float b = accB[r*4+cj];
                vals[3*cj+0] = vxI*b + s2I*accE0[r*4+cj];
                vals[3*cj+1] = vyI*b + s2I*accE1[r*4+cj];
                vals[3*cj+2] = vzI*b + s2I*accE2[r*4+cj];
            }
            float* orow = out + (rbase + rw)*OUTD + 128 + 3*c4;
            *reinterpret_cast<float4*>(orow)     = make_float4(vals[0],vals[1],vals[2],vals[3]);
            *reinterpret_cast<float4*>(orow + 4) = make_float4(vals[4],vals[5],vals[6],vals[7]);
            *reinterpret_cast<float4*>(orow + 8) = make_float4(vals[8],vals[9],vals[10],vals[11]);
        }
    }
    __syncthreads();

    // ---------------- stage U: featC = cross(x1v, v2) * INV6 ----------------
    {
        float qf[48];
        #pragma unroll
        for (int c = 0; c < 12; ++c) {
            float4 v = ld4(x1r + 128 + 48*q + 4*c);
            qf[4*c+0]=v.x; qf[4*c+1]=v.y; qf[4*c+2]=v.z; qf[4*c+3]=v.w;
        }
        #pragma unroll
        for (int i = 0; i < 16; ++i) {
            const int u = 16*q + i;
            const float a0 = qf[3*i+0], a1 = qf[3*i+1], a2 = qf[3*i+2];
            frS[u]       = (a1*vz - a2*vy) * INV6;
            frS[64 + u]  = (a2*vx - a0*vz) * INV6;
            frS[128 + u] = (a0*vy - a1*vx) * INV6;
        }
    }
    __syncthreads();

    // ---------------- P4: out2 (kept from R6) ----------------
    {
        const float* frC = feat + row * FSTR;
        float accC[24];
        #pragma unroll
        for (int i = 0; i < 24; ++i) accC[i] = 0.f;
        const int wb = wvu * 8;

        #pragma unroll 2
        for (int ut = 0; ut < 16; ++ut) {
            f32x4 g0 = *reinterpret_cast<const f32x4*>(frC + 4*ut);
            f32x4 g1 = *reinterpret_cast<const f32x4*>(frC + 64 + 4*ut);
            f32x4 g2 = *reinterpret_cast<const f32x4*>(frC + 128 + 4*ut);
            #pragma unroll
            for (int du = 0; du < 4; ++du) {
                const float b0 = g0[du], b1 = g1[du], b2 = g2[du];
                const float* wp = w112 + (4*ut+du)*32 + wb;
                float4 wa = ld4(wp);
                float4 wbq = ld4(wp + 4);
                const float wvals[8] = {wa.x, wa.y, wa.z, wa.w, wbq.x, wbq.y, wbq.z, wbq.w};
                #pragma unroll
                for (int wl = 0; wl < 8; ++wl) {
                    accC[3*wl+0] += b0 * wvals[wl];
                    accC[3*wl+1] += b1 * wvals[wl];
                    accC[3*wl+2] += b2 * wvals[wl];
                }
            }
        }
        float* orow = out + (rbase + row)*OUTD + 320 + 24*wvu;
        #pragma unroll
        for (int qq = 0; qq < 6; ++qq)
            *reinterpret_cast<float4*>(orow + 4*qq) =
                make_float4(accC[4*qq], accC[4*qq+1], accC[4*qq+2], accC[4*qq+3]);
    }

    #undef FMAS8
    #undef FMAS4
    #undef LOADW8
    #undef LOADW4
}

extern "C" void kernel_launch(void* const* d_in, const int* in_sizes, int n_in,
                              void* d_out, int out_size, void* d_ws, size_t ws_size,
                              hipStream_t stream) {
    const float* x1   = (const float*)d_in[0];
    const float* x2   = (const float*)d_in[1];
    const float* w000 = (const float*)d_in[2];
    const float* w011 = (const float*)d_in[3];
    const float* w101 = (const float*)d_in[4];
    const float* w110 = (const float*)d_in[5];
    const float* w112 = (const float*)d_in[6];
    // d_in[7] = w3j111 — folded analytically (cross product / sqrt6).
    float* out = (float*)d_out;

    tp_valu_v7<<<dim3(NBLK), dim3(256), 0, stream>>>(
        x1, x2, w000, w011, w101, w110, w112, out);
}